// Round 1
// baseline (1655.257 us; speedup 1.0000x reference)
//
#include <hip/hip_runtime.h>

// Problem dims
#define TOKS    65536      // 16 * 4096
#define D_IN    512
#define D_E     256
#define NCODES  1024

// ---------------------------------------------------------------------------
// Row squared-norm: dst[row] = sum_j src[row][j]^2, 256 cols. One wave/row.
// ---------------------------------------------------------------------------
__global__ __launch_bounds__(256) void rownorm_kernel(
        const float* __restrict__ src, float* __restrict__ dst) {
    int row  = blockIdx.x * 4 + (threadIdx.x >> 6);
    int lane = threadIdx.x & 63;
    float4 v = *(const float4*)(src + (long)row * 256 + lane * 4);
    float s = v.x * v.x + v.y * v.y + v.z * v.z + v.w * v.w;
    #pragma unroll
    for (int off = 32; off; off >>= 1) s += __shfl_xor(s, off, 64);
    if (lane == 0) dst[row] = s;
}

// ---------------------------------------------------------------------------
// Tiled fp32 GEMM: C[M,N] = A[M,K] @ B[N,K]^T  (both row-major).
// 64x64 tile, 256 threads, 4x4 microtile, k-chunk 64, LDS k-major +4 pad.
// GATHER: A row m is codebook[code[m]] instead of A[m].
// ---------------------------------------------------------------------------
template <int K, int N, bool GATHER>
__global__ __launch_bounds__(256) void gemm_kernel(
        const float* __restrict__ A, const float* __restrict__ B,
        float* __restrict__ C, const int* __restrict__ code) {
    __shared__ float As[64][68];
    __shared__ float Bs[64][68];

    const int m0 = blockIdx.y * 64;
    const int n0 = blockIdx.x * 64;
    const int tid = threadIdx.x;
    const int r  = tid >> 2, fi = tid & 3;   // staging: 4 threads per row
    const int ty = tid >> 4, tx = tid & 15;  // microtile grid 16x16

    const float* Arow;
    if constexpr (GATHER) {
        Arow = A + (long)code[m0 + r] * K;
    } else {
        Arow = A + (long)(m0 + r) * K;
    }
    const float* Brow = B + (long)(n0 + r) * K;

    float acc[4][4] = {};

    for (int k0 = 0; k0 < K; k0 += 64) {
        #pragma unroll
        for (int j = 0; j < 4; ++j) {
            int c4 = fi * 4 + j;             // float4 index within 64-wide k chunk
            float4 a = *(const float4*)(Arow + k0 + c4 * 4);
            float4 b = *(const float4*)(Brow + k0 + c4 * 4);
            As[c4 * 4 + 0][r] = a.x; As[c4 * 4 + 1][r] = a.y;
            As[c4 * 4 + 2][r] = a.z; As[c4 * 4 + 3][r] = a.w;
            Bs[c4 * 4 + 0][r] = b.x; Bs[c4 * 4 + 1][r] = b.y;
            Bs[c4 * 4 + 2][r] = b.z; Bs[c4 * 4 + 3][r] = b.w;
        }
        __syncthreads();
        #pragma unroll 8
        for (int k = 0; k < 64; ++k) {
            float4 a4 = *(const float4*)&As[k][4 * ty];
            float4 b4 = *(const float4*)&Bs[k][4 * tx];
            float av[4] = {a4.x, a4.y, a4.z, a4.w};
            float bv[4] = {b4.x, b4.y, b4.z, b4.w};
            #pragma unroll
            for (int i = 0; i < 4; ++i)
                #pragma unroll
                for (int j = 0; j < 4; ++j)
                    acc[i][j] += av[i] * bv[j];
        }
        __syncthreads();
    }

    #pragma unroll
    for (int i = 0; i < 4; ++i) {
        float4 v = make_float4(acc[i][0], acc[i][1], acc[i][2], acc[i][3]);
        *(float4*)(C + (long)(m0 + 4 * ty + i) * N + n0 + 4 * tx) = v;
    }
}

// ---------------------------------------------------------------------------
// Fused distance + argmin + loss kernel.
// Block = 64 tokens, 256 threads = 4 waves; wave w owns tokens [16w,16w+16).
// Lanes are the code dimension: lane l handles codes cbase+l and cbase+64+l.
// dist = |c|^2 - 2 z_e.c  (token-constant |z_e|^2 dropped for argmin,
// re-added for the loss: |z_q - z_e|^2 = best_dist + |z_e|^2).
// ---------------------------------------------------------------------------
__global__ __launch_bounds__(256) void argmin_kernel(
        const float* __restrict__ z_e, const float* __restrict__ cb,
        const float* __restrict__ cnorm, const float* __restrict__ znorm,
        int* __restrict__ code_i, float* __restrict__ code_f,
        float* __restrict__ loss_acc) {
    __shared__ float ze[64][68];     // [token][k], +4 pad
    __shared__ float cbt[128][68];   // [code][k], +4 pad

    const int t0  = blockIdx.x * 64;
    const int tid = threadIdx.x;
    const int w    = tid >> 6;
    const int lane = tid & 63;

    float best_d[16];
    int   best_i[16];
    #pragma unroll
    for (int t = 0; t < 16; ++t) { best_d[t] = 3.4e38f; best_i[t] = 0; }

    for (int ct = 0; ct < 8; ++ct) {
        const int cbase = ct * 128;
        float acc0[16] = {};
        float acc1[16] = {};

        for (int kc = 0; kc < 4; ++kc) {
            const int k0 = kc * 64;
            {   // stage z_e tile: 64 tok x 64 k
                int r = tid >> 2, fi = tid & 3;
                #pragma unroll
                for (int j = 0; j < 4; ++j) {
                    int c4 = fi * 4 + j;
                    float4 v = *(const float4*)(z_e + (long)(t0 + r) * 256 + k0 + c4 * 4);
                    *(float4*)&ze[r][c4 * 4] = v;
                }
                // stage codebook tile: 128 codes x 64 k
                int row = tid >> 1, g = tid & 1;
                #pragma unroll
                for (int j = 0; j < 8; ++j) {
                    int c4 = g * 8 + j;
                    float4 v = *(const float4*)(cb + (long)(cbase + row) * 256 + k0 + c4 * 4);
                    *(float4*)&cbt[row][c4 * 4] = v;
                }
            }
            __syncthreads();
            #pragma unroll 2
            for (int k4 = 0; k4 < 16; ++k4) {
                const int k = k4 * 4;
                float4 ca = *(const float4*)&cbt[lane][k];
                float4 cbv = *(const float4*)&cbt[lane + 64][k];
                #pragma unroll
                for (int t = 0; t < 16; ++t) {
                    float4 zv = *(const float4*)&ze[w * 16 + t][k];
                    acc0[t] += zv.x * ca.x + zv.y * ca.y + zv.z * ca.z + zv.w * ca.w;
                    acc1[t] += zv.x * cbv.x + zv.y * cbv.y + zv.z * cbv.z + zv.w * cbv.w;
                }
            }
            __syncthreads();
        }

        const float cn0 = cnorm[cbase + lane];
        const float cn1 = cnorm[cbase + 64 + lane];
        #pragma unroll
        for (int t = 0; t < 16; ++t) {
            float d0 = cn0 - 2.0f * acc0[t];
            float d1 = cn1 - 2.0f * acc1[t];
            float d = d0; int idx = cbase + lane;
            if (d1 < d0) { d = d1; idx = cbase + 64 + lane; }
            #pragma unroll
            for (int off = 32; off; off >>= 1) {
                float od = __shfl_xor(d, off, 64);
                int   oi = __shfl_xor(idx, off, 64);
                if (od < d || (od == d && oi < idx)) { d = od; idx = oi; }
            }
            if (d < best_d[t]) { best_d[t] = d; best_i[t] = idx; }
        }
    }

    if (lane == 0) {
        const int tb = t0 + w * 16;
        float lsum = 0.0f;
        #pragma unroll
        for (int t = 0; t < 16; ++t) {
            int tok = tb + t;
            code_i[tok] = best_i[t];
            code_f[tok] = (float)best_i[t];
            lsum += best_d[t] + znorm[tok];
        }
        // batch = tok >> 12 (4096 tokens/batch; 64-token block never straddles)
        atomicAdd(loss_acc + (tb >> 12), lsum);
    }
}

// ---------------------------------------------------------------------------
// Scale summed losses by 1/(4096*256) and write both loss outputs.
// ---------------------------------------------------------------------------
__global__ void finalize_kernel(const float* __restrict__ loss_acc,
                                float* __restrict__ out_losses) {
    int i = threadIdx.x;
    if (i < 16) {
        float v = loss_acc[i] * (1.0f / 1048576.0f);
        out_losses[i]      = v;   // commitment_loss
        out_losses[16 + i] = v;   // codebook_loss (same forward value)
    }
}

// ---------------------------------------------------------------------------
extern "C" void kernel_launch(void* const* d_in, const int* in_sizes, int n_in,
                              void* d_out, int out_size, void* d_ws, size_t ws_size,
                              hipStream_t stream) {
    const float* z      = (const float*)d_in[0];  // [16,4096,512]
    const float* cb     = (const float*)d_in[1];  // [1024,256]
    const float* w_down = (const float*)d_in[2];  // [256,512]
    const float* w_up   = (const float*)d_in[3];  // [512,256]

    float* out        = (float*)d_out;
    float* z_out      = out;                       // 33554432 floats
    float* out_losses = out + 33554432;            // 16 + 16 floats
    float* code_f     = out + 33554464;            // 65536 floats

    char* ws = (char*)d_ws;
    float* z_e      = (float*)ws;                       // 65536*256*4 = 64 MiB
    int*   code_i   = (int*)  (ws + 67108864);          // 256 KiB
    float* cnorm    = (float*)(ws + 67371008);          // 4 KiB
    float* znorm    = (float*)(ws + 67375104);          // 256 KiB
    float* loss_acc = (float*)(ws + 67637248);          // 64 B

    hipMemsetAsync(loss_acc, 0, 64, stream);

    // codebook row norms
    rownorm_kernel<<<NCODES / 4, 256, 0, stream>>>(cb, cnorm);

    // GEMM1: z_e = z @ w_down^T   [65536,512]x[512,256]
    gemm_kernel<512, 256, false><<<dim3(256 / 64, TOKS / 64), 256, 0, stream>>>(
        z, w_down, z_e, nullptr);

    // |z_e|^2 per token
    rownorm_kernel<<<TOKS / 4, 256, 0, stream>>>(z_e, znorm);

    // distances + argmin + losses
    argmin_kernel<<<TOKS / 64, 256, 0, stream>>>(
        z_e, cb, cnorm, znorm, code_i, code_f, loss_acc);

    // GEMM2: z_out = codebook[code] @ w_up^T   [65536,256]x[256,512]
    gemm_kernel<256, 512, true><<<dim3(512 / 64, TOKS / 64), 256, 0, stream>>>(
        cb, w_up, z_out, code_i);

    finalize_kernel<<<1, 64, 0, stream>>>(loss_acc, out_losses);
}

// Round 2
// 1219.400 us; speedup vs baseline: 1.3574x; 1.3574x over previous
//
#include <hip/hip_runtime.h>

// Problem dims
#define TOKS    65536      // 16 * 4096
#define D_IN    512
#define D_E     256
#define NCODES  1024

// ---------------------------------------------------------------------------
// Row squared-norm: dst[row] = sum_j src[row][j]^2, 256 cols. One wave/row.
// ---------------------------------------------------------------------------
__global__ __launch_bounds__(256) void rownorm_kernel(
        const float* __restrict__ src, float* __restrict__ dst) {
    int row  = blockIdx.x * 4 + (threadIdx.x >> 6);
    int lane = threadIdx.x & 63;
    float4 v = *(const float4*)(src + (long)row * 256 + lane * 4);
    float s = v.x * v.x + v.y * v.y + v.z * v.z + v.w * v.w;
    #pragma unroll
    for (int off = 32; off; off >>= 1) s += __shfl_xor(s, off, 64);
    if (lane == 0) dst[row] = s;
}

// ---------------------------------------------------------------------------
// Tiled fp32 GEMM v2: C[M,N] = A[M,K] @ B[N,K]^T (both row-major).
// 128x128 tile, 256 threads, 8x8 microtile, k-chunk 64, k-major LDS (+4 pad).
// GATHER: A row m is codebook[code[m]].
// ---------------------------------------------------------------------------
template <int K, int N, bool GATHER>
__global__ __launch_bounds__(256, 2) void gemm_kernel(
        const float* __restrict__ A, const float* __restrict__ B,
        float* __restrict__ C, const int* __restrict__ code) {
    __shared__ float As[64][132];   // [k][m], stride 132 (mod 32 = 4)
    __shared__ float Bs[64][132];   // [k][n]

    const int m0  = blockIdx.y * 128;
    const int n0  = blockIdx.x * 128;
    const int tid = threadIdx.x;
    const int r   = tid >> 1, h = tid & 1;   // staging: 2 threads per row
    const int ty  = tid >> 4, tx = tid & 15; // microtile 16x16 of 8x8

    const float* Arow;
    if constexpr (GATHER) {
        Arow = A + (long)code[m0 + r] * K;
    } else {
        Arow = A + (long)(m0 + r) * K;
    }
    const float* Brow = B + (long)(n0 + r) * K;

    float acc[8][8] = {};

    for (int k0 = 0; k0 < K; k0 += 64) {
        __syncthreads();
        #pragma unroll
        for (int j = 0; j < 8; ++j) {
            int kk = h * 32 + j * 4;
            float4 a = *(const float4*)(Arow + k0 + kk);
            float4 b = *(const float4*)(Brow + k0 + kk);
            As[kk + 0][r] = a.x; As[kk + 1][r] = a.y;
            As[kk + 2][r] = a.z; As[kk + 3][r] = a.w;
            Bs[kk + 0][r] = b.x; Bs[kk + 1][r] = b.y;
            Bs[kk + 2][r] = b.z; Bs[kk + 3][r] = b.w;
        }
        __syncthreads();
        #pragma unroll 4
        for (int k = 0; k < 64; ++k) {
            float4 a0 = *(const float4*)&As[k][ty * 8];
            float4 a1 = *(const float4*)&As[k][ty * 8 + 4];
            float4 b0 = *(const float4*)&Bs[k][tx * 8];
            float4 b1 = *(const float4*)&Bs[k][tx * 8 + 4];
            float av[8] = {a0.x, a0.y, a0.z, a0.w, a1.x, a1.y, a1.z, a1.w};
            float bv[8] = {b0.x, b0.y, b0.z, b0.w, b1.x, b1.y, b1.z, b1.w};
            #pragma unroll
            for (int i = 0; i < 8; ++i)
                #pragma unroll
                for (int j = 0; j < 8; ++j)
                    acc[i][j] += av[i] * bv[j];
        }
    }

    #pragma unroll
    for (int i = 0; i < 8; ++i) {
        float* crow = C + (long)(m0 + ty * 8 + i) * N + n0 + tx * 8;
        *(float4*)crow       = make_float4(acc[i][0], acc[i][1], acc[i][2], acc[i][3]);
        *(float4*)(crow + 4) = make_float4(acc[i][4], acc[i][5], acc[i][6], acc[i][7]);
    }
}

// ---------------------------------------------------------------------------
// Fused distance + argmin + loss kernel v2.
// Block = 64 tokens, 4 waves; wave w owns tokens [16w, 16w+16).
// Code tiles of 256: lane l owns codes {tile*256 + c*64 + l, c=0..3}.
// Codebook tile stored TRANSPOSED in LDS (ct[k][code]) -> lane reads are
// consecutive-address ds_read_b32 (conflict-free). ze reads are wave-uniform
// broadcasts (free). acc[4][16] register block: 256 FMA per 32 LDS ops.
// dist = |c|^2 - 2 z_e.c  (|z_e|^2 re-added only for the loss).
// ---------------------------------------------------------------------------
__global__ __launch_bounds__(256, 3) void argmin_kernel(
        const float* __restrict__ z_e, const float* __restrict__ cb,
        const float* __restrict__ cnorm, const float* __restrict__ znorm,
        int* __restrict__ code_i, float* __restrict__ code_f,
        float* __restrict__ loss_acc) {
    __shared__ float ze[64][36];     // [tok][k-chunk], 144 B rows (16B aligned)
    __shared__ float ct[32][260];    // [k][code], transposed

    const int t0   = blockIdx.x * 64;
    const int tid  = threadIdx.x;
    const int w    = tid >> 6;
    const int lane = tid & 63;

    float best_d[16];
    int   best_i[16];
    #pragma unroll
    for (int t = 0; t < 16; ++t) { best_d[t] = 3.4e38f; best_i[t] = 0; }

    for (int tile = 0; tile < 4; ++tile) {
        const int cb0 = tile * 256;
        float acc[4][16] = {};

        for (int kc = 0; kc < 8; ++kc) {
            const int k0 = kc * 32;
            __syncthreads();
            {   // stage ze chunk: 64 tok x 32 k; 4 threads/row, 2 float4 each
                int zr = tid >> 2, fi = tid & 3;
                #pragma unroll
                for (int j = 0; j < 2; ++j) {
                    int kk = fi * 8 + j * 4;
                    float4 v = *(const float4*)(z_e + (long)(t0 + zr) * 256 + k0 + kk);
                    *(float4*)&ze[zr][kk] = v;
                }
                // stage codebook chunk transposed: 256 codes x 32 k
                const float* crow = cb + (long)(cb0 + tid) * 256 + k0;
                #pragma unroll
                for (int j = 0; j < 8; ++j) {
                    float4 v = *(const float4*)(crow + j * 4);
                    ct[j * 4 + 0][tid] = v.x; ct[j * 4 + 1][tid] = v.y;
                    ct[j * 4 + 2][tid] = v.z; ct[j * 4 + 3][tid] = v.w;
                }
            }
            __syncthreads();

            #pragma unroll 2
            for (int k4 = 0; k4 < 8; ++k4) {
                const int k = k4 * 4;
                float4 zv[16];
                #pragma unroll
                for (int t = 0; t < 16; ++t)
                    zv[t] = *(const float4*)&ze[w * 16 + t][k];
                #pragma unroll
                for (int c = 0; c < 4; ++c) {
                    float cv0 = ct[k + 0][c * 64 + lane];
                    float cv1 = ct[k + 1][c * 64 + lane];
                    float cv2 = ct[k + 2][c * 64 + lane];
                    float cv3 = ct[k + 3][c * 64 + lane];
                    #pragma unroll
                    for (int t = 0; t < 16; ++t) {
                        acc[c][t] += zv[t].x * cv0;
                        acc[c][t] += zv[t].y * cv1;
                        acc[c][t] += zv[t].z * cv2;
                        acc[c][t] += zv[t].w * cv3;
                    }
                }
            }
        }

        // fold this tile into running best (ties -> smaller index everywhere)
        float cn[4];
        #pragma unroll
        for (int c = 0; c < 4; ++c) cn[c] = cnorm[cb0 + c * 64 + lane];
        #pragma unroll
        for (int t = 0; t < 16; ++t) {
            float d = cn[0] - 2.0f * acc[0][t];
            int idx = cb0 + lane;
            #pragma unroll
            for (int c = 1; c < 4; ++c) {
                float dc = cn[c] - 2.0f * acc[c][t];
                if (dc < d) { d = dc; idx = cb0 + c * 64 + lane; }
            }
            #pragma unroll
            for (int off = 32; off; off >>= 1) {
                float od = __shfl_xor(d, off, 64);
                int   oi = __shfl_xor(idx, off, 64);
                if (od < d || (od == d && oi < idx)) { d = od; idx = oi; }
            }
            if (d < best_d[t]) { best_d[t] = d; best_i[t] = idx; }
        }
    }

    if (lane == 0) {
        const int tb = t0 + w * 16;
        float lsum = 0.0f;
        #pragma unroll
        for (int t = 0; t < 16; ++t) {
            int tok = tb + t;
            code_i[tok] = best_i[t];
            code_f[tok] = (float)best_i[t];
            lsum += best_d[t] + znorm[tok];
        }
        // batch = tok >> 12 (4096 tokens/batch; 64-token block never straddles)
        atomicAdd(loss_acc + (tb >> 12), lsum);
    }
}

// ---------------------------------------------------------------------------
// Scale summed losses by 1/(4096*256) and write both loss outputs.
// ---------------------------------------------------------------------------
__global__ void finalize_kernel(const float* __restrict__ loss_acc,
                                float* __restrict__ out_losses) {
    int i = threadIdx.x;
    if (i < 16) {
        float v = loss_acc[i] * (1.0f / 1048576.0f);
        out_losses[i]      = v;   // commitment_loss
        out_losses[16 + i] = v;   // codebook_loss (same forward value)
    }
}

// ---------------------------------------------------------------------------
extern "C" void kernel_launch(void* const* d_in, const int* in_sizes, int n_in,
                              void* d_out, int out_size, void* d_ws, size_t ws_size,
                              hipStream_t stream) {
    const float* z      = (const float*)d_in[0];  // [16,4096,512]
    const float* cb     = (const float*)d_in[1];  // [1024,256]
    const float* w_down = (const float*)d_in[2];  // [256,512]
    const float* w_up   = (const float*)d_in[3];  // [512,256]

    float* out        = (float*)d_out;
    float* z_out      = out;                       // 33554432 floats
    float* out_losses = out + 33554432;            // 16 + 16 floats
    float* code_f     = out + 33554464;            // 65536 floats

    char* ws = (char*)d_ws;
    float* z_e      = (float*)ws;                       // 64 MiB
    int*   code_i   = (int*)  (ws + 67108864);          // 256 KiB
    float* cnorm    = (float*)(ws + 67371008);          // 4 KiB
    float* znorm    = (float*)(ws + 67375104);          // 256 KiB
    float* loss_acc = (float*)(ws + 67637248);          // 64 B

    hipMemsetAsync(loss_acc, 0, 64, stream);

    // codebook row norms
    rownorm_kernel<<<NCODES / 4, 256, 0, stream>>>(cb, cnorm);

    // GEMM1: z_e = z @ w_down^T   [65536,512]x[512,256]
    gemm_kernel<512, 256, false><<<dim3(256 / 128, TOKS / 128), 256, 0, stream>>>(
        z, w_down, z_e, nullptr);

    // |z_e|^2 per token
    rownorm_kernel<<<TOKS / 4, 256, 0, stream>>>(z_e, znorm);

    // distances + argmin + losses
    argmin_kernel<<<TOKS / 64, 256, 0, stream>>>(
        z_e, cb, cnorm, znorm, code_i, code_f, loss_acc);

    // GEMM2: z_out = codebook[code] @ w_up^T   [65536,256]x[256,512]
    gemm_kernel<256, 512, true><<<dim3(512 / 128, TOKS / 128), 256, 0, stream>>>(
        cb, w_up, z_out, code_i);

    finalize_kernel<<<1, 64, 0, stream>>>(loss_acc, out_losses);
}